// Round 1
// baseline (138.688 us; speedup 1.0000x reference)
//
#include <hip/hip_runtime.h>

#define NUSR 8192
#define HDIM 256

typedef __attribute__((ext_vector_type(8))) __bf16 bf16x8;
typedef __attribute__((ext_vector_type(4))) float f32x4;

union frag_u { bf16x8 v; unsigned short u[8]; unsigned int d[4]; };

// f32 -> bf16 RNE
__device__ __forceinline__ unsigned int f2bf(float f) {
  unsigned u = __builtin_bit_cast(unsigned, f);
  u += 0x7FFFu + ((u >> 16) & 1u);
  return u >> 16;
}
__device__ __forceinline__ unsigned int f2bf2(float lo, float hi) {
  return f2bf(lo) | (f2bf(hi) << 16);
}
__device__ __forceinline__ float sigmoidf_fast(float x) {
  float e = __builtin_amdgcn_exp2f(x * -1.44269504088896340736f);
  return __builtin_amdgcn_rcpf(1.0f + e);
}

// PX layout (proj in MFMA-B fragment order), ushort offsets:
//   PX[(col>>4)*4096 + (k>>5)*512 + ((k>>3)&3)*128 + (col&15)*8 + (k&7)]
// -> B-frag for (col16 ct, kb) = 16B at PX + ct*4096 + kb*512 + lane*8 (lane-linear).

// ---------------------------------------------------------------------------
// k1_fused: ONE launch doing both prep stages concurrently.
//   blocks 0..127   : proj -> PX. Each block owns 64 yb rows (4 groups of 16);
//                     wave w = st-quarter, W fragments converted inline from f32
//                     (A-frag is loaded once per (st,kb) and reused for 4 row
//                     groups, so W traffic = 256 KB/block = 32 MB total).
//   blocks 128..511 : ya -> yabf bf16 conversion (coalesced 32B/thread chunks).
//   block 511       : additionally zeroes svec + done counters.
// ---------------------------------------------------------------------------
__global__ __launch_bounds__(256) void k1_fused(
    const float* __restrict__ ya, const float* __restrict__ yb,
    const float* __restrict__ W, const float* __restrict__ bvec,
    unsigned short* __restrict__ yabf, unsigned short* __restrict__ PX,
    float* __restrict__ svec, unsigned int* __restrict__ done)
{
  const int b   = blockIdx.x;   // 0..511
  const int tid = threadIdx.x;

  if (b < 128) {
    // ---- proj part ----
    const int lane = tid & 63;
    const int w    = tid >> 6;   // st-quarter 0..3
    const int q    = lane >> 4;
    const int i    = lane & 15;

    frag_u B[4][8]; // 4 row-groups x 8 k-blocks of yb, bf16 B-frags
#pragma unroll
    for (int g = 0; g < 4; ++g) {
      const float* ybrow = yb + (size_t)(b * 64 + g * 16 + i) * HDIM;
#pragma unroll
      for (int kb = 0; kb < 8; ++kb) {
        float4 v0 = *(const float4*)&ybrow[kb * 32 + q * 8];
        float4 v1 = *(const float4*)&ybrow[kb * 32 + q * 8 + 4];
        B[g][kb].d[0] = f2bf2(v0.x, v0.y); B[g][kb].d[1] = f2bf2(v0.z, v0.w);
        B[g][kb].d[2] = f2bf2(v1.x, v1.y); B[g][kb].d[3] = f2bf2(v1.z, v1.w);
      }
    }

#pragma unroll
    for (int t = 0; t < 4; ++t) {
      const int st = w * 4 + t;
      f32x4 acc[4] = {{0.f,0.f,0.f,0.f},{0.f,0.f,0.f,0.f},
                      {0.f,0.f,0.f,0.f},{0.f,0.f,0.f,0.f}};
#pragma unroll
      for (int kb = 0; kb < 8; ++kb) {
        // inline-convert the W A-frag (same values the old WX path produced)
        const float* wr = W + (size_t)(st * 16 + i) * HDIM + kb * 32 + q * 8;
        float4 w0 = *(const float4*)wr;
        float4 w1 = *(const float4*)(wr + 4);
        frag_u Af;
        Af.d[0] = f2bf2(w0.x, w0.y); Af.d[1] = f2bf2(w0.z, w0.w);
        Af.d[2] = f2bf2(w1.x, w1.y); Af.d[3] = f2bf2(w1.z, w1.w);
#pragma unroll
        for (int g = 0; g < 4; ++g)
          acc[g] = __builtin_amdgcn_mfma_f32_16x16x32_bf16(Af.v, B[g][kb].v, acc[g], 0, 0, 0);
      }
      float4 bias = *(const float4*)&bvec[st * 16 + q * 4];
#pragma unroll
      for (int g = 0; g < 4; ++g) {
        const int jg = b * 4 + g;
        unsigned v0 = f2bf2(acc[g][0] + bias.x, acc[g][1] + bias.y);
        unsigned v1 = f2bf2(acc[g][2] + bias.z, acc[g][3] + bias.w);
        size_t off = (size_t)jg * 4096 + (size_t)(st >> 1) * 512
                   + (size_t)(((st & 1) << 1) | (q >> 1)) * 128 + i * 8 + ((q & 1) * 4);
        *(uint2*)(PX + off) = make_uint2(v0, v1);
      }
    }
  } else {
    // ---- ya -> bf16 conversion part (384 blocks, 262144 uint4 chunks) ----
    const int id = (b - 128) * 256 + tid;  // 0..98303
    const float4* src = (const float4*)ya;
    uint4* dst = (uint4*)yabf;
#pragma unroll
    for (int u = 0; u < 3; ++u) {
      int d = id + u * 98304;
      if (d < 262144) {
        float4 a = src[d * 2];
        float4 c = src[d * 2 + 1];
        uint4 o = { f2bf2(a.x, a.y), f2bf2(a.z, a.w),
                    f2bf2(c.x, c.y), f2bf2(c.z, c.w) };
        dst[d] = o;
      }
    }
    if (b == 511) {
      float4 z = {0.f, 0.f, 0.f, 0.f};
      float4* sv = (float4*)svec;
#pragma unroll
      for (int u = 0; u < 8; ++u) sv[u * 256 + tid] = z;
      if (tid < 32) done[tid] = 0u;
    }
  }
}

// ---------------------------------------------------------------------------
// k2: s[i] += sum_j sigmoid( ya[i] . proj[j] )  — core UNCHANGED from baseline.
// grid (32,16) x 256 thr: 4 waves x 64 rows (A = 128 regs, held whole kernel).
// Double-buffered LDS (2 x 16 KB); stage-loads for tile t+1 issued right after
// the barrier opening tile t's compute, so the vmcnt(0) drain is nearly free.
// NEW: fused k3 tail — the 16th finisher of each 256-row group (counted via
// device-scope done[x]) broadcasts svec/256 into the output rows. No spinning,
// so no residency requirement.
// ---------------------------------------------------------------------------
__global__ __launch_bounds__(256, 2) void k2_score(
    const unsigned short* __restrict__ yabf, const unsigned short* __restrict__ PX,
    float* __restrict__ svec, unsigned int* __restrict__ done,
    float* __restrict__ out, const int fuse_tail)
{
  __shared__ __align__(16) unsigned short bs[2][8192]; // 2 x 16 KB
  __shared__ unsigned int lastv;
  const int tid  = threadIdx.x;
  const int lane = tid & 63;
  const int w    = tid >> 6;
  const int quad = lane >> 4;
  const int l15  = lane & 15;
  const int rbase = blockIdx.x * 256 + w * 64;
  const int cg16  = blockIdx.y * 32;          // col16-group base (512 cols)

  // A-frags: 64 ya rows per wave, direct bf16 16B loads
  frag_u A[4][8];
#pragma unroll
  for (int g = 0; g < 4; ++g) {
    const unsigned short* src = yabf + (size_t)(rbase + g * 16 + l15) * HDIM;
#pragma unroll
    for (int kb = 0; kb < 8; ++kb)
      A[g][kb].v = *(const bf16x8*)&src[kb * 32 + quad * 8];
  }

  const unsigned short* psrc = PX + (size_t)cg16 * 4096; // this block's 256 KB slice

  float rs[4][4] = {{0.f,0.f,0.f,0.f},{0.f,0.f,0.f,0.f},
                    {0.f,0.f,0.f,0.f},{0.f,0.f,0.f,0.f}};

  // stage tile 0 into buffer 0 (16 KB = 1024 x 16B chunks, 4 per thread)
#pragma unroll
  for (int p = 0; p < 4; ++p) {
    int c = p * 256 + tid;
    __builtin_amdgcn_global_load_lds(
        (const __attribute__((address_space(1))) unsigned int*)(const void*)(psrc + c * 8),
        (__attribute__((address_space(3))) unsigned int*)(void*)(&bs[0][0] + c * 8),
        16, 0, 0);
  }
  __syncthreads(); // tile 0 visible

  for (int t = 0; t < 16; ++t) {           // 16 tiles x 32 cols = 512 cols
    // issue stage of tile t+1 into the other buffer — overlaps compute below
    if (t < 15) {
      const unsigned short* src = psrc + (size_t)(t + 1) * 8192;
      unsigned short* dst = &bs[(t + 1) & 1][0];
#pragma unroll
      for (int p = 0; p < 4; ++p) {
        int c = p * 256 + tid;
        __builtin_amdgcn_global_load_lds(
            (const __attribute__((address_space(1))) unsigned int*)(const void*)(src + c * 8),
            (__attribute__((address_space(3))) unsigned int*)(void*)(dst + c * 8),
            16, 0, 0);
      }
    }
    // compute tile t from bs[t&1]
    const unsigned short* buf = &bs[t & 1][0];
#pragma unroll
    for (int tt = 0; tt < 2; ++tt) {
      f32x4 acc[4] = {{0.f,0.f,0.f,0.f},{0.f,0.f,0.f,0.f},
                      {0.f,0.f,0.f,0.f},{0.f,0.f,0.f,0.f}};
#pragma unroll
      for (int kb = 0; kb < 8; ++kb) {
        bf16x8 bfrag = *(const bf16x8*)&buf[(tt * 512 + kb * 64 + lane) * 8];
#pragma unroll
        for (int g = 0; g < 4; ++g)
          acc[g] = __builtin_amdgcn_mfma_f32_16x16x32_bf16(A[g][kb].v, bfrag, acc[g], 0, 0, 0);
      }
#pragma unroll
      for (int g = 0; g < 4; ++g)
#pragma unroll
        for (int r = 0; r < 4; ++r)
          rs[g][r] += sigmoidf_fast(acc[g][r]);
    }
    __syncthreads(); // drains t+1 loads (had full compute phase) + buffer reuse
  }

  // reduce over the 16 col-lanes within each quad group
#pragma unroll
  for (int off = 1; off < 16; off <<= 1)
#pragma unroll
    for (int g = 0; g < 4; ++g)
#pragma unroll
      for (int r = 0; r < 4; ++r)
        rs[g][r] += __shfl_xor(rs[g][r], off, 64);

  if (l15 == 0) {
#pragma unroll
    for (int g = 0; g < 4; ++g)
#pragma unroll
      for (int r = 0; r < 4; ++r)
        atomicAdd(&svec[rbase + g * 16 + quad * 4 + r], rs[g][r]);
  }

  if (!fuse_tail) return;

  // ---- fused k3 tail ----
  __syncthreads(); // vmcnt(0): all 4 waves' svec atomics complete
  if (tid == 0)
    lastv = __hip_atomic_fetch_add(&done[blockIdx.x], 1u,
                                   __ATOMIC_ACQ_REL, __HIP_MEMORY_SCOPE_AGENT);
  __syncthreads();
  if (lastv == 15u) {
    // last of the 16 col-slices for this 256-row group: write the output rows.
    const int rb = blockIdx.x * 256;
    const float inv = 1.0f / 256.0f;
#pragma unroll 4
    for (int u = 0; u < 64; ++u) {
      int row = u * 4 + w;  // wave-uniform row -> coalesced 1 KB row writes
      float s = __hip_atomic_load(&svec[rb + row],
                                  __ATOMIC_RELAXED, __HIP_MEMORY_SCOPE_AGENT);
      float v = s * inv;
      float4 o = {v, v, v, v};
      ((float4*)out)[(size_t)(rb + row) * 64 + lane] = o;
    }
  }
}

// ---------------------------------------------------------------------------
// k3: fallback only (workspace too small to avoid aliasing PX with d_out)
// ---------------------------------------------------------------------------
__global__ __launch_bounds__(256) void k3_bcast(
    const float* __restrict__ svec, float* __restrict__ out)
{
  int idx = blockIdx.x * 256 + threadIdx.x;
  int row = idx >> 6;
  float v = svec[row] * (1.0f / 256.0f);
  float4 o = {v, v, v, v};
  ((float4*)out)[idx] = o;
}

extern "C" void kernel_launch(void* const* d_in, const int* in_sizes, int n_in,
                              void* d_out, int out_size, void* d_ws, size_t ws_size,
                              hipStream_t stream) {
  (void)in_sizes; (void)n_in; (void)out_size;
  const float* ya = (const float*)d_in[0];
  const float* yb = (const float*)d_in[1];
  const float* W  = (const float*)d_in[2];
  const float* bv = (const float*)d_in[3];
  float* out = (float*)d_out;

  char* ws = (char*)d_ws;
  unsigned short *PX, *yabf;
  float* svec;
  unsigned int* done;
  int fuse;
  const size_t need = (8ull << 20) + (64ull << 10);
  if (ws_size >= need) {
    PX   = (unsigned short*)ws;
    yabf = (unsigned short*)(ws + (4 << 20));
    svec = (float*)(ws + (8 << 20));
    done = (unsigned int*)(ws + (8 << 20) + (32 << 10));
    fuse = 1;
  } else {
    PX   = (unsigned short*)d_out;                 // aliases out -> keep k3 separate
    yabf = (unsigned short*)((char*)d_out + (4 << 20));
    svec = (float*)ws;
    done = (unsigned int*)(ws + (32 << 10));
    fuse = 0;
  }

  k1_fused<<<512, 256, 0, stream>>>(ya, yb, W, bv, yabf, PX, svec, done);
  k2_score<<<dim3(32, 16), 256, 0, stream>>>(yabf, PX, svec, done, out, fuse);
  if (!fuse) k3_bcast<<<2048, 256, 0, stream>>>(svec, out);
}

// Round 2
// 120.344 us; speedup vs baseline: 1.1524x; 1.1524x over previous
//
#include <hip/hip_runtime.h>

#define NUSR 8192
#define HDIM 256

typedef __attribute__((ext_vector_type(8))) __bf16 bf16x8;
typedef __attribute__((ext_vector_type(4))) float f32x4;

union frag_u { bf16x8 v; unsigned short u[8]; unsigned int d[4]; };

// f32 -> bf16 RNE
__device__ __forceinline__ unsigned int f2bf(float f) {
  unsigned u = __builtin_bit_cast(unsigned, f);
  u += 0x7FFFu + ((u >> 16) & 1u);
  return u >> 16;
}
__device__ __forceinline__ unsigned int f2bf2(float lo, float hi) {
  return f2bf(lo) | (f2bf(hi) << 16);
}
__device__ __forceinline__ float sigmoidf_fast(float x) {
  float e = __builtin_amdgcn_exp2f(x * -1.44269504088896340736f);
  return __builtin_amdgcn_rcpf(1.0f + e);
}

// PX layout (proj in MFMA-B fragment order), ushort offsets:
//   PX[(col>>4)*4096 + (k>>5)*512 + ((k>>3)&3)*128 + (col&15)*8 + (k&7)]
// -> B-frag for (col16 ct, kb) = 16B at PX + ct*4096 + kb*512 + lane*8 (lane-linear).

// ---------------------------------------------------------------------------
// k1_fused: ONE launch doing both prep stages concurrently.
//   blocks 0..255   : proj -> PX. Each block owns 32 yb rows (2 groups of 16);
//                     wave w = st-quarter, W fragments converted inline from f32.
//   blocks 256..511 : ya -> yabf bf16 conversion (coalesced 32B/thread chunks).
//   block 511       : additionally zeroes svec.
// ---------------------------------------------------------------------------
__global__ __launch_bounds__(256) void k1_fused(
    const float* __restrict__ ya, const float* __restrict__ yb,
    const float* __restrict__ W, const float* __restrict__ bvec,
    unsigned short* __restrict__ yabf, unsigned short* __restrict__ PX,
    float* __restrict__ svec)
{
  const int b   = blockIdx.x;   // 0..511
  const int tid = threadIdx.x;

  if (b < 256) {
    // ---- proj part ----
    const int lane = tid & 63;
    const int w    = tid >> 6;   // st-quarter 0..3
    const int q    = lane >> 4;
    const int i    = lane & 15;

    frag_u B[2][8]; // 2 row-groups x 8 k-blocks of yb, bf16 B-frags
#pragma unroll
    for (int g = 0; g < 2; ++g) {
      const float* ybrow = yb + (size_t)(b * 32 + g * 16 + i) * HDIM;
#pragma unroll
      for (int kb = 0; kb < 8; ++kb) {
        float4 v0 = *(const float4*)&ybrow[kb * 32 + q * 8];
        float4 v1 = *(const float4*)&ybrow[kb * 32 + q * 8 + 4];
        B[g][kb].d[0] = f2bf2(v0.x, v0.y); B[g][kb].d[1] = f2bf2(v0.z, v0.w);
        B[g][kb].d[2] = f2bf2(v1.x, v1.y); B[g][kb].d[3] = f2bf2(v1.z, v1.w);
      }
    }

#pragma unroll
    for (int t = 0; t < 4; ++t) {
      const int st = w * 4 + t;
      f32x4 acc[2] = {{0.f,0.f,0.f,0.f},{0.f,0.f,0.f,0.f}};
#pragma unroll
      for (int kb = 0; kb < 8; ++kb) {
        // inline-convert the W A-frag (same values the old WX path produced)
        const float* wr = W + (size_t)(st * 16 + i) * HDIM + kb * 32 + q * 8;
        float4 w0 = *(const float4*)wr;
        float4 w1 = *(const float4*)(wr + 4);
        frag_u Af;
        Af.d[0] = f2bf2(w0.x, w0.y); Af.d[1] = f2bf2(w0.z, w0.w);
        Af.d[2] = f2bf2(w1.x, w1.y); Af.d[3] = f2bf2(w1.z, w1.w);
#pragma unroll
        for (int g = 0; g < 2; ++g)
          acc[g] = __builtin_amdgcn_mfma_f32_16x16x32_bf16(Af.v, B[g][kb].v, acc[g], 0, 0, 0);
      }
      float4 bias = *(const float4*)&bvec[st * 16 + q * 4];
#pragma unroll
      for (int g = 0; g < 2; ++g) {
        const int jg = b * 2 + g;
        unsigned v0 = f2bf2(acc[g][0] + bias.x, acc[g][1] + bias.y);
        unsigned v1 = f2bf2(acc[g][2] + bias.z, acc[g][3] + bias.w);
        size_t off = (size_t)jg * 4096 + (size_t)(st >> 1) * 512
                   + (size_t)(((st & 1) << 1) | (q >> 1)) * 128 + i * 8 + ((q & 1) * 4);
        *(uint2*)(PX + off) = make_uint2(v0, v1);
      }
    }
  } else {
    // ---- ya -> bf16 conversion part (256 blocks, 262144 uint4 chunks) ----
    const int id = (b - 256) * 256 + tid;  // 0..65535
    const float4* src = (const float4*)ya;
    uint4* dst = (uint4*)yabf;
#pragma unroll
    for (int u = 0; u < 4; ++u) {
      int d = id + u * 65536;
      float4 a = src[d * 2];
      float4 c = src[d * 2 + 1];
      uint4 o = { f2bf2(a.x, a.y), f2bf2(a.z, a.w),
                  f2bf2(c.x, c.y), f2bf2(c.z, c.w) };
      dst[d] = o;
    }
    if (b == 511) {
      float4 z = {0.f, 0.f, 0.f, 0.f};
      float4* sv = (float4*)svec;
#pragma unroll
      for (int u = 0; u < 8; ++u) sv[u * 256 + tid] = z;
    }
  }
}

// ---------------------------------------------------------------------------
// k2: s[i] += sum_j sigmoid( ya[i] . proj[j] )
// BARRIER-FREE version: no LDS, no __syncthreads. Each wave owns 64 ya rows
// (A-frags held in regs the whole kernel) and streams its 512-col PX slice
// directly from global (L2) as lane-linear 16B B-frag loads, register-double-
// buffered one 16-col segment ahead. Waves are fully independent -> no
// lockstep stalls; loads overlap MFMA+sigmoid of the previous segment.
// XCD-aware block swizzle: the 512 blocks are mapped so each XCD sees only
// 2 of the 16 PX col-slices (512 KB) -> PX stays L2-resident per XCD.
// ---------------------------------------------------------------------------
__global__ __launch_bounds__(256, 2) void k2_score(
    const unsigned short* __restrict__ yabf, const unsigned short* __restrict__ PX,
    float* __restrict__ svec)
{
  const int tid  = threadIdx.x;
  const int lane = tid & 63;
  const int w    = tid >> 6;
  const int quad = lane >> 4;
  const int l15  = lane & 15;

  // swizzle: bid = k*8 + xcd (default round-robin) -> XCD 'xcd' gets
  // by in {2*xcd, 2*xcd+1}, bx = k&31. 64 blocks per XCD, 2 col-slices.
  const int bid = blockIdx.x;          // 0..511
  const int xcd = bid & 7;
  const int k   = bid >> 3;            // 0..63
  const int by  = xcd * 2 + (k >> 5);  // 0..15
  const int bx  = k & 31;              // 0..31

  const int rbase = bx * 256 + w * 64;
  const int cg16  = by * 32;           // col16-group base (512 cols)

  // A-frags: 64 ya rows per wave, direct bf16 16B loads
  frag_u A[4][8];
#pragma unroll
  for (int g = 0; g < 4; ++g) {
    const unsigned short* src = yabf + (size_t)(rbase + g * 16 + l15) * HDIM;
#pragma unroll
    for (int kb = 0; kb < 8; ++kb)
      A[g][kb].v = *(const bf16x8*)&src[kb * 32 + quad * 8];
  }

  const unsigned short* psrc = PX + (size_t)cg16 * 4096; // 32 col16-segs

  float rs[4][4] = {{0.f,0.f,0.f,0.f},{0.f,0.f,0.f,0.f},
                    {0.f,0.f,0.f,0.f},{0.f,0.f,0.f,0.f}};

  frag_u Ba[8], Bb[8];

#define LOADSEG(DST, SEG)                                                   \
  do {                                                                      \
    const unsigned short* _s = psrc + (size_t)(SEG) * 4096;                 \
    _Pragma("unroll")                                                       \
    for (int kb = 0; kb < 8; ++kb)                                          \
      DST[kb].v = *(const bf16x8*)&_s[kb * 512 + lane * 8];                 \
  } while (0)

#define COMPUTESEG(BUF)                                                     \
  do {                                                                      \
    f32x4 acc[4] = {{0.f,0.f,0.f,0.f},{0.f,0.f,0.f,0.f},                    \
                    {0.f,0.f,0.f,0.f},{0.f,0.f,0.f,0.f}};                   \
    _Pragma("unroll")                                                       \
    for (int kb = 0; kb < 8; ++kb) {                                        \
      _Pragma("unroll")                                                     \
      for (int g = 0; g < 4; ++g)                                           \
        acc[g] = __builtin_amdgcn_mfma_f32_16x16x32_bf16(                   \
            A[g][kb].v, BUF[kb].v, acc[g], 0, 0, 0);                        \
    }                                                                       \
    _Pragma("unroll")                                                       \
    for (int g = 0; g < 4; ++g)                                             \
      _Pragma("unroll")                                                     \
      for (int r = 0; r < 4; ++r)                                           \
        rs[g][r] += sigmoidf_fast(acc[g][r]);                               \
  } while (0)

  LOADSEG(Ba, 0);                      // prologue: seg 0 in flight

  for (int t = 0; t < 16; ++t) {       // 32 segs of 16 cols, 2 per iteration
    LOADSEG(Bb, 2 * t + 1);            // prefetch odd seg (overlaps compute)
    COMPUTESEG(Ba);                    // compute seg 2t
    if (t < 15)
      LOADSEG(Ba, 2 * t + 2);          // prefetch next even seg
    COMPUTESEG(Bb);                    // compute seg 2t+1
  }
#undef LOADSEG
#undef COMPUTESEG

  // reduce over the 16 col-lanes within each quad group
#pragma unroll
  for (int off = 1; off < 16; off <<= 1)
#pragma unroll
    for (int g = 0; g < 4; ++g)
#pragma unroll
      for (int r = 0; r < 4; ++r)
        rs[g][r] += __shfl_xor(rs[g][r], off, 64);

  if (l15 == 0) {
#pragma unroll
    for (int g = 0; g < 4; ++g)
#pragma unroll
      for (int r = 0; r < 4; ++r)
        atomicAdd(&svec[rbase + g * 16 + quad * 4 + r], rs[g][r]);
  }
}

// ---------------------------------------------------------------------------
// k3: out[i][k] = s[i] / 256
// ---------------------------------------------------------------------------
__global__ __launch_bounds__(256) void k3_bcast(
    const float* __restrict__ svec, float* __restrict__ out)
{
  int idx = blockIdx.x * 256 + threadIdx.x;
  int row = idx >> 6;
  float v = svec[row] * (1.0f / 256.0f);
  float4 o = {v, v, v, v};
  ((float4*)out)[idx] = o;
}

extern "C" void kernel_launch(void* const* d_in, const int* in_sizes, int n_in,
                              void* d_out, int out_size, void* d_ws, size_t ws_size,
                              hipStream_t stream) {
  (void)in_sizes; (void)n_in; (void)out_size;
  const float* ya = (const float*)d_in[0];
  const float* yb = (const float*)d_in[1];
  const float* W  = (const float*)d_in[2];
  const float* bv = (const float*)d_in[3];
  float* out = (float*)d_out;

  char* ws = (char*)d_ws;
  unsigned short *PX, *yabf;
  float* svec;
  const size_t need = (8ull << 20) + (32ull << 10);
  if (ws_size >= need) {
    PX   = (unsigned short*)ws;
    yabf = (unsigned short*)(ws + (4 << 20));
    svec = (float*)(ws + (8 << 20));
  } else {
    PX   = (unsigned short*)d_out;                 // aliases out; k3 rewrites all
    yabf = (unsigned short*)((char*)d_out + (4 << 20));
    svec = (float*)ws;
  }

  k1_fused<<<512, 256, 0, stream>>>(ya, yb, W, bv, yabf, PX, svec);
  k2_score<<<512, 256, 0, stream>>>(yabf, PX, svec);
  k3_bcast<<<2048, 256, 0, stream>>>(svec, out);
}